// Round 1
// baseline (368.183 us; speedup 1.0000x reference)
//
#include <hip/hip_runtime.h>
#include <hip/hip_bf16.h>
#include <math.h>

#define KS 5
#define CIN 3
#define KN 64
#define HIN 128
#define HO 124
#define ROWF (HIN * CIN)          // 384 floats per input row
#define NW 75                     // 5*5*3 weights per output channel
#define NOUT (128LL * 124 * 124 * 64)  // 125,960,192

// ---------------- KL scalar kernel (one wave) ----------------
__global__ void kl_kernel(const float* __restrict__ w_mu,
                          const float* __restrict__ w_sigma,
                          float* __restrict__ out_kl) {
    int kn = threadIdx.x;  // 64 threads
    float s = 0.f;
#pragma unroll
    for (int i = 0; i < NW; ++i) {
        float m = w_mu[i * KN + kn];
        s = fmaf(m, m, s);
    }
    float lv = w_sigma[kn];
    float sp = log1pf(expf(lv));
    float val = 1.0f + lv - sp - s * (1.0f / 75.0f);
    // wave-64 reduction
#pragma unroll
    for (int off = 32; off > 0; off >>= 1) val += __shfl_down(val, off);
    if (kn == 0) {
        float kl = -(val / 64.0f);
        if (isnan(kl) || isinf(kl)) kl = 1e-5f;
        out_kl[0] = kl;
    }
}

// ---------------- main conv + Sigma kernel ----------------
// One block per (b, ho). 256 threads = 4 waves; lane = kn, wave owns 31 cols.
__global__ __launch_bounds__(256, 2) void conv_kernel(
    const float* __restrict__ mu_in,
    const float* __restrict__ w_mu,
    const float* __restrict__ w_sigma,
    float* __restrict__ mu_out,
    float* __restrict__ sig_out) {

    __shared__ float s_in[1984];   // 5 rows * 384 + pad (tail batches over-read)
    __shared__ float s_w[NW * KN]; // 4800
    __shared__ float s_sp[KN];
    __shared__ float s_cs[HIN];
    __shared__ float s_ssn[HO];

    const int bid = blockIdx.x;
    const int b = bid / HO;
    const int ho = bid % HO;
    const int tid = threadIdx.x;

    // stage 5 contiguous input rows: 1920 f32 = 480 float4
    const float* src = mu_in + (size_t)(b * HIN + ho) * ROWF;
    for (int i = tid; i < 480; i += 256)
        reinterpret_cast<float4*>(s_in)[i] =
            reinterpret_cast<const float4*>(src)[i];
    // stage weights: 4800 f32 = 1200 float4
    for (int i = tid; i < 1200; i += 256)
        reinterpret_cast<float4*>(s_w)[i] =
            reinterpret_cast<const float4*>(w_mu)[i];
    if (tid < KN) {
        float lv = w_sigma[tid];
        s_sp[tid] = log1pf(expf(lv));
    }
    __syncthreads();

    // per-column sum of squares over 5 rows x 3 ch
    if (tid < HIN) {
        float cs = 0.f;
#pragma unroll
        for (int r = 0; r < KS; ++r)
#pragma unroll
            for (int c = 0; c < CIN; ++c) {
                float v = s_in[r * ROWF + tid * CIN + c];
                cs = fmaf(v, v, cs);
            }
        s_cs[tid] = cs;
    }
    __syncthreads();
    if (tid < HO) {
        float ss = s_cs[tid] + s_cs[tid + 1] + s_cs[tid + 2] + s_cs[tid + 3] +
                   s_cs[tid + 4];
        s_ssn[tid] = ss * (1.0f / 75.0f);
    }
    __syncthreads();

    const int lane = tid & 63;
    const int wid = tid >> 6;

    // preload this lane's 75 weights (kn = lane); index [r*15 + dc*3 + c]
    float wreg[NW];
#pragma unroll
    for (int i = 0; i < NW; ++i) wreg[i] = s_w[i * KN + lane];
    const float sp = s_sp[lane];

    const int wo_base = wid * 31;
    const size_t orow = (size_t)(b * HO + ho) * HO * (size_t)KN;

#pragma unroll
    for (int t = 0; t < 4; ++t) {
        const int s0 = wo_base + t * 8;
        const int nvalid = (t < 3) ? 8 : 7;  // 31 = 8+8+8+7
        float acc[8] = {0.f, 0.f, 0.f, 0.f, 0.f, 0.f, 0.f, 0.f};
#pragma unroll
        for (int r = 0; r < KS; ++r) {
            float v[36];
            const int base = r * ROWF + s0 * CIN;
#pragma unroll
            for (int j = 0; j < 36; ++j) v[j] = s_in[base + j];
#pragma unroll
            for (int p = 0; p < 8; ++p)
#pragma unroll
                for (int q = 0; q < 15; ++q)
                    acc[p] = fmaf(v[3 * p + q], wreg[r * 15 + q], acc[p]);
        }
        for (int p = 0; p < nvalid; ++p) {
            const int wo = s0 + p;
            const size_t oidx = orow + (size_t)wo * KN + lane;
            mu_out[oidx] = acc[p];
            sig_out[oidx] = sp * s_ssn[wo];
        }
    }
}

extern "C" void kernel_launch(void* const* d_in, const int* in_sizes, int n_in,
                              void* d_out, int out_size, void* d_ws,
                              size_t ws_size, hipStream_t stream) {
    const float* mu_in = (const float*)d_in[0];
    const float* w_mu = (const float*)d_in[1];
    const float* w_sigma = (const float*)d_in[2];
    float* out = (float*)d_out;

    float* mu_out = out;                    // N floats
    float* sig_out = out + NOUT;            // N floats
    float* kl_out = out + 2 * NOUT;         // 1 float

    conv_kernel<<<128 * HO, 256, 0, stream>>>(mu_in, w_mu, w_sigma, mu_out,
                                              sig_out);
    kl_kernel<<<1, 64, 0, stream>>>(w_mu, w_sigma, kl_out);
}

// Round 2
// 265.754 us; speedup vs baseline: 1.3854x; 1.3854x over previous
//
#include <hip/hip_runtime.h>
#include <hip/hip_bf16.h>
#include <math.h>

#define KS 5
#define CIN 3
#define KN 64
#define HIN 128
#define HO 124
#define ROWF (HIN * CIN)               // 384 floats per input row
#define NOUT (128LL * 124 * 124 * 64)  // 125,960,192

typedef short bfrag8 __attribute__((ext_vector_type(8)));  // 8 bf16 (4 VGPR)
typedef float ffrag4 __attribute__((ext_vector_type(4)));  // 4 f32 acc

// round-to-nearest-even f32 -> bf16 bits (finite inputs)
__device__ __forceinline__ unsigned short f2bf(float f) {
    union { float f; unsigned u; } x;
    x.f = f;
    unsigned r = x.u + 0x7fffu + ((x.u >> 16) & 1u);
    return (unsigned short)(r >> 16);
}

// ---------------- KL scalar kernel (one wave) ----------------
__global__ void kl_kernel(const float* __restrict__ w_mu,
                          const float* __restrict__ w_sigma,
                          float* __restrict__ out_kl) {
    int kn = threadIdx.x;  // 64 threads
    float s = 0.f;
#pragma unroll
    for (int i = 0; i < 75; ++i) {
        float m = w_mu[i * KN + kn];
        s = fmaf(m, m, s);
    }
    float lv = w_sigma[kn];
    float sp = log1pf(expf(lv));
    float val = 1.0f + lv - sp - s * (1.0f / 75.0f);
#pragma unroll
    for (int off = 32; off > 0; off >>= 1) val += __shfl_down(val, off);
    if (kn == 0) {
        float kl = -(val / 64.0f);
        if (isnan(kl) || isinf(kl)) kl = 1e-5f;
        out_kl[0] = kl;
    }
}

// ---------------- main conv + Sigma kernel (bf16 MFMA implicit GEMM) -------
// One block per (b, ho). 256 threads = 4 waves. M=128 wo-rows (124 valid),
// N=64 kn, K=96 (k = r*16 + dc*3 + c; positions t==15 and k>=80 are ZERO on
// the weight side, so padded A positions may hold arbitrary finite values).
__global__ __launch_bounds__(256, 4) void conv_kernel(
    const float* __restrict__ mu_in,
    const float* __restrict__ w_mu,
    const float* __restrict__ w_sigma,
    float* __restrict__ mu_out,
    float* __restrict__ sig_out) {

    __shared__ __align__(16) float s_in[2336];          // 5 rows + zero row + pad
    __shared__ __align__(16) unsigned short s_w[64 * 104];  // bf16 [n][k] pad 104
    __shared__ float s_sp[KN];
    __shared__ float s_cs[HIN];
    __shared__ float s_ssn[HO];

    const int bid = blockIdx.x;
    const int b = bid / HO;
    const int ho = bid % HO;
    const int tid = threadIdx.x;

    // stage 5 contiguous input rows: 1920 f32 = 480 float4
    const float* src = mu_in + (size_t)(b * HIN + ho) * ROWF;
    for (int i = tid; i < 480; i += 256)
        reinterpret_cast<float4*>(s_in)[i] =
            reinterpret_cast<const float4*>(src)[i];
    // zero the "row 5" + pad region (finite zeros for padded-K A reads)
    for (int i = 1920 + tid; i < 2336; i += 256) s_in[i] = 0.f;

    // weights -> LDS, transposed to [n][k] bf16, k = r*16 + t (t = dc*3+c)
    {
        const int n = tid >> 2;            // 64 rows, 4 threads each
        const int kbase = (tid & 3) * 26;  // 4*26 = 104
#pragma unroll
        for (int kk = 0; kk < 26; ++kk) {
            const int k = kbase + kk;
            float v = 0.f;
            if (k < 80) {
                const int r = k >> 4, t = k & 15;
                if (t < 15) v = w_mu[(r * 15 + t) * KN + n];
            }
            s_w[n * 104 + k] = f2bf(v);
        }
    }
    if (tid < KN) s_sp[tid] = log1pf(expf(w_sigma[tid]));
    __syncthreads();

    // per-column sum of squares over 5 rows x 3 ch (f32, exact path for Sigma)
    if (tid < HIN) {
        float cs = 0.f;
#pragma unroll
        for (int r = 0; r < KS; ++r)
#pragma unroll
            for (int c = 0; c < CIN; ++c) {
                float v = s_in[r * ROWF + tid * CIN + c];
                cs = fmaf(v, v, cs);
            }
        s_cs[tid] = cs;
    }
    __syncthreads();
    if (tid < HO) {
        float ss = s_cs[tid] + s_cs[tid + 1] + s_cs[tid + 2] + s_cs[tid + 3] +
                   s_cs[tid + 4];
        s_ssn[tid] = ss * (1.0f / 75.0f);
    }
    __syncthreads();

    const int lane = tid & 63;
    const int wid = tid >> 6;
    const int lhi = lane >> 4;  // 0..3
    const int llo = lane & 15;

    ffrag4 acc[2][4];
#pragma unroll
    for (int m = 0; m < 2; ++m)
#pragma unroll
        for (int n = 0; n < 4; ++n) acc[m][n] = (ffrag4){0.f, 0.f, 0.f, 0.f};

#pragma unroll
    for (int ks = 0; ks < 3; ++ks) {
        const int k0 = ks * 32 + lhi * 8;   // this lane's 8-k run
        // B fragments: lane holds col n = nt*16+llo, 8 contiguous k
        bfrag8 bfr[4];
#pragma unroll
        for (int nt = 0; nt < 4; ++nt)
            bfr[nt] = *reinterpret_cast<const bfrag8*>(
                &s_w[(nt * 16 + llo) * 104 + k0]);

        const int r = k0 >> 4;    // kernel row (5 = zero row)
        const int off = k0 & 15;  // 0 or 8 within the 16-wide r-run
#pragma unroll
        for (int mt = 0; mt < 2; ++mt) {
            const int wo = wid * 32 + mt * 16 + llo;  // A row = output col
            const float* ap = &s_in[r * ROWF + wo * CIN + off];
            bfrag8 afr;
#pragma unroll
            for (int j = 0; j < 8; ++j) afr[j] = (short)f2bf(ap[j]);
#pragma unroll
            for (int nt = 0; nt < 4; ++nt)
                acc[mt][nt] = __builtin_amdgcn_mfma_f32_16x16x32_bf16(
                    afr, bfr[nt], acc[mt][nt], 0, 0, 0);
        }
    }

    // epilogue: C layout col=lane&15 (kn), row=(lane>>4)*4+reg (wo-local)
    float spv[4];
#pragma unroll
    for (int nt = 0; nt < 4; ++nt) spv[nt] = s_sp[nt * 16 + llo];

    const size_t orow = (size_t)(b * HO + ho) * (size_t)(HO * KN);
#pragma unroll
    for (int mt = 0; mt < 2; ++mt) {
#pragma unroll
        for (int rg = 0; rg < 4; ++rg) {
            const int wo = wid * 32 + mt * 16 + lhi * 4 + rg;
            if (wo < HO) {
                const float ssn = s_ssn[wo];
                const size_t obase = orow + (size_t)wo * KN;
#pragma unroll
                for (int nt = 0; nt < 4; ++nt) {
                    const int kn = nt * 16 + llo;
                    mu_out[obase + kn] = acc[mt][nt][rg];
                    sig_out[obase + kn] = spv[nt] * ssn;
                }
            }
        }
    }
}

extern "C" void kernel_launch(void* const* d_in, const int* in_sizes, int n_in,
                              void* d_out, int out_size, void* d_ws,
                              size_t ws_size, hipStream_t stream) {
    const float* mu_in = (const float*)d_in[0];
    const float* w_mu = (const float*)d_in[1];
    const float* w_sigma = (const float*)d_in[2];
    float* out = (float*)d_out;

    float* mu_out = out;             // N floats
    float* sig_out = out + NOUT;     // N floats
    float* kl_out = out + 2 * NOUT;  // 1 float

    conv_kernel<<<128 * HO, 256, 0, stream>>>(mu_in, w_mu, w_sigma, mu_out,
                                              sig_out);
    kl_kernel<<<1, 64, 0, stream>>>(w_mu, w_sigma, kl_out);
}

// Round 3
// 247.983 us; speedup vs baseline: 1.4847x; 1.0717x over previous
//
#include <hip/hip_runtime.h>
#include <hip/hip_bf16.h>
#include <math.h>

#define KS 5
#define CIN 3
#define KN 64
#define HIN 128
#define HO 124
#define ROWF (HIN * CIN)               // 384 floats per input row
#define NOUT (128LL * 124 * 124 * 64)  // 125,960,192
#define KP 104                         // padded K (bf16 elems) for LDS banking

typedef short bfrag8 __attribute__((ext_vector_type(8)));  // 8 bf16 (4 VGPR)
typedef float ffrag4 __attribute__((ext_vector_type(4)));  // 4 f32 acc

// round-to-nearest-even f32 -> bf16 bits (finite inputs)
__device__ __forceinline__ unsigned short f2bf(float f) {
    union { float f; unsigned u; } x;
    x.f = f;
    unsigned r = x.u + 0x7fffu + ((x.u >> 16) & 1u);
    return (unsigned short)(r >> 16);
}

// ---------------- one-time prep: weight transpose->bf16 + softplus ---------
// ws layout: [0 .. 13312) bf16 weights [n=64][k=KP], [13312 .. 13568) f32 sp[64]
__global__ void prep_kernel(const float* __restrict__ w_mu,
                            const float* __restrict__ w_sigma,
                            unsigned short* __restrict__ w_bf,
                            float* __restrict__ sp_out) {
    const int tid = threadIdx.x;       // 256
    const int n = tid >> 2;            // 64 rows, 4 threads each
    const int kbase = (tid & 3) * 26;  // 4*26 = 104
#pragma unroll
    for (int kk = 0; kk < 26; ++kk) {
        const int k = kbase + kk;
        float v = 0.f;
        if (k < 80) {
            const int r = k >> 4, t = k & 15;
            if (t < 15) v = w_mu[(r * 15 + t) * KN + n];
        }
        w_bf[n * KP + k] = f2bf(v);
    }
    if (tid < KN) sp_out[tid] = log1pf(expf(w_sigma[tid]));
}

// ---------------- KL scalar kernel (one wave) ----------------
__global__ void kl_kernel(const float* __restrict__ w_mu,
                          const float* __restrict__ w_sigma,
                          float* __restrict__ out_kl) {
    int kn = threadIdx.x;  // 64 threads
    float s = 0.f;
#pragma unroll
    for (int i = 0; i < 75; ++i) {
        float m = w_mu[i * KN + kn];
        s = fmaf(m, m, s);
    }
    float lv = w_sigma[kn];
    float sp = log1pf(expf(lv));
    float val = 1.0f + lv - sp - s * (1.0f / 75.0f);
#pragma unroll
    for (int off = 32; off > 0; off >>= 1) val += __shfl_down(val, off);
    if (kn == 0) {
        float kl = -(val / 64.0f);
        if (isnan(kl) || isinf(kl)) kl = 1e-5f;
        out_kl[0] = kl;
    }
}

// ---------------- main conv + Sigma kernel (bf16 MFMA implicit GEMM) -------
// One block per (b, ho). 256 threads = 4 waves.
// GEMM: A = weights (M=64 kn), B = input im2col (N=128 wo), K=96.
// k = r*16 + t (t = dc*3+c); weight is ZERO at t==15 and k>=80, so input-side
// pad positions may hold arbitrary FINITE values (all pads explicitly zeroed).
__global__ __launch_bounds__(256, 3) void conv_kernel(
    const float* __restrict__ mu_in,
    const unsigned short* __restrict__ w_bf,
    const float* __restrict__ sp_in,
    float* __restrict__ mu_out,
    float* __restrict__ sig_out) {

    __shared__ __align__(16) float s_in[1952];            // 5 rows f32 + zero pad
    __shared__ __align__(16) unsigned short s_x[128 * KP];  // im2col bf16 [wo][k]
    __shared__ __align__(16) unsigned short s_w[KN * KP];   // weights bf16 [kn][k]
    __shared__ float s_sp[KN];
    __shared__ float s_cs[HIN];
    __shared__ float s_ssn[HIN];

    const int bid = blockIdx.x;
    const int b = bid / HO;
    const int ho = bid % HO;
    const int tid = threadIdx.x;

    // stage 5 contiguous input rows: 1920 f32 = 480 float4
    const float* src = mu_in + (size_t)(b * HIN + ho) * ROWF;
    for (int i = tid; i < 480; i += 256)
        reinterpret_cast<float4*>(s_in)[i] =
            reinterpret_cast<const float4*>(src)[i];
    if (tid < 32) s_in[1920 + tid] = 0.f;  // finite zeros for row-4 overrun
    // stage pre-transposed bf16 weights: 13312 B = 832 float4
    for (int i = tid; i < 832; i += 256)
        reinterpret_cast<float4*>(s_w)[i] =
            reinterpret_cast<const float4*>(w_bf)[i];
    if (tid < KN) s_sp[tid] = sp_in[tid];
    __syncthreads();

    // per-column sum of squares over 5 rows x 3 ch (f32 exact path for Sigma)
    if (tid < HIN) {
        float cs = 0.f;
#pragma unroll
        for (int r = 0; r < KS; ++r)
#pragma unroll
            for (int c = 0; c < CIN; ++c) {
                float v = s_in[r * ROWF + tid * CIN + c];
                cs = fmaf(v, v, cs);
            }
        s_cs[tid] = cs;
    }
    __syncthreads();

    // patch-ss / 75 per output column (+ im2col bf16 conversion, same phase)
    if (tid < HIN) {
        float v = 0.f;
        if (tid < HO)
            v = (s_cs[tid] + s_cs[tid + 1] + s_cs[tid + 2] + s_cs[tid + 3] +
                 s_cs[tid + 4]) * (1.0f / 75.0f);
        s_ssn[tid] = v;
    }
    // im2col: 640 (r,wo) pairs, each converts 16 f32 -> 16 bf16 (t=15 garbage ok)
    for (int i = tid; i < 640; i += 256) {
        const int r = i >> 7;    // 0..4
        const int wo = i & 127;  // 0..127
        const float* p = &s_in[r * ROWF + wo * CIN];
        unsigned u[8];
#pragma unroll
        for (int j = 0; j < 8; ++j)
            u[j] = (unsigned)f2bf(p[2 * j]) | ((unsigned)f2bf(p[2 * j + 1]) << 16);
        uint4* dst = reinterpret_cast<uint4*>(&s_x[wo * KP + r * 16]);
        dst[0] = make_uint4(u[0], u[1], u[2], u[3]);
        dst[1] = make_uint4(u[4], u[5], u[6], u[7]);
    }
    // zero k = 80..95 of every wo row (read by ks=2, annihilated by zero wts)
    for (int i = tid; i < 1024; i += 256) {
        const int wo = i >> 3, j = i & 7;
        reinterpret_cast<unsigned*>(s_x)[wo * (KP / 2) + 40 + j] = 0u;
    }
    __syncthreads();

    const int lane = tid & 63;
    const int wid = tid >> 6;
    const int llo = lane & 15;
    const int lhi = lane >> 4;

    // preload A fragments (weights): lane row kn = mt*16+llo, k-run = ks*32+lhi*8
    bfrag8 afr[4][3];
#pragma unroll
    for (int mt = 0; mt < 4; ++mt)
#pragma unroll
        for (int ks = 0; ks < 3; ++ks)
            afr[mt][ks] = *reinterpret_cast<const bfrag8*>(
                &s_w[(mt * 16 + llo) * KP + ks * 32 + lhi * 8]);

    ffrag4 acc[2][4];  // [ntile][mtile]
#pragma unroll
    for (int nt = 0; nt < 2; ++nt)
#pragma unroll
        for (int mt = 0; mt < 4; ++mt) acc[nt][mt] = (ffrag4){0.f, 0.f, 0.f, 0.f};

#pragma unroll
    for (int nt = 0; nt < 2; ++nt) {
        const int wo = (wid * 2 + nt) * 16 + llo;  // B col
#pragma unroll
        for (int ks = 0; ks < 3; ++ks) {
            bfrag8 bfr = *reinterpret_cast<const bfrag8*>(
                &s_x[wo * KP + ks * 32 + lhi * 8]);
#pragma unroll
            for (int mt = 0; mt < 4; ++mt)
                acc[nt][mt] = __builtin_amdgcn_mfma_f32_16x16x32_bf16(
                    afr[mt][ks], bfr, acc[nt][mt], 0, 0, 0);
        }
    }

    // epilogue: C col = llo = wo-local, row = lhi*4+rg = kn-local (contiguous!)
    float4 sp4[4];
#pragma unroll
    for (int mt = 0; mt < 4; ++mt)
        sp4[mt] = *reinterpret_cast<const float4*>(&s_sp[mt * 16 + lhi * 4]);

    const size_t orow = (size_t)(b * HO + ho) * (size_t)(HO * KN);
#pragma unroll
    for (int nt = 0; nt < 2; ++nt) {
        const int wo = (wid * 2 + nt) * 16 + llo;
        if (wo < HO) {
            const float ssn = s_ssn[wo];
            const size_t obase = orow + (size_t)wo * KN;
#pragma unroll
            for (int mt = 0; mt < 4; ++mt) {
                const int knb = mt * 16 + lhi * 4;
                *reinterpret_cast<float4*>(&mu_out[obase + knb]) =
                    make_float4(acc[nt][mt][0], acc[nt][mt][1], acc[nt][mt][2],
                                acc[nt][mt][3]);
                *reinterpret_cast<float4*>(&sig_out[obase + knb]) =
                    make_float4(sp4[mt].x * ssn, sp4[mt].y * ssn,
                                sp4[mt].z * ssn, sp4[mt].w * ssn);
            }
        }
    }
}

extern "C" void kernel_launch(void* const* d_in, const int* in_sizes, int n_in,
                              void* d_out, int out_size, void* d_ws,
                              size_t ws_size, hipStream_t stream) {
    const float* mu_in = (const float*)d_in[0];
    const float* w_mu = (const float*)d_in[1];
    const float* w_sigma = (const float*)d_in[2];
    float* out = (float*)d_out;

    float* mu_out = out;             // N floats
    float* sig_out = out + NOUT;     // N floats
    float* kl_out = out + 2 * NOUT;  // 1 float

    unsigned short* w_bf = (unsigned short*)d_ws;            // 13312 B
    float* sp_ws = (float*)((char*)d_ws + KN * KP * 2);      // 256 B

    prep_kernel<<<1, 256, 0, stream>>>(w_mu, w_sigma, w_bf, sp_ws);
    conv_kernel<<<128 * HO, 256, 0, stream>>>(mu_in, w_bf, sp_ws, mu_out,
                                              sig_out);
    kl_kernel<<<1, 64, 0, stream>>>(w_mu, w_sigma, kl_out);
}

// Round 4
// 242.366 us; speedup vs baseline: 1.5191x; 1.0232x over previous
//
#include <hip/hip_runtime.h>
#include <hip/hip_bf16.h>
#include <math.h>

#define KN 64
#define HO 124
#define KP 104
#define NOUT (128LL * 124 * 124 * 64)  // 125,960,192
#define NG 31                          // 124/4 ho-groups per image

typedef short bfrag8 __attribute__((ext_vector_type(8)));  // 8 bf16
typedef float ffrag4 __attribute__((ext_vector_type(4)));  // 4 f32 acc

// round-to-nearest-even f32 -> bf16 bits (finite inputs)
__device__ __forceinline__ unsigned short f2bf(float f) {
    union { float f; unsigned u; } x;
    x.f = f;
    unsigned r = x.u + 0x7fffu + ((x.u >> 16) & 1u);
    return (unsigned short)(r >> 16);
}
__device__ __forceinline__ unsigned pack2(float a, float b) {
    return (unsigned)f2bf(a) | ((unsigned)f2bf(b) << 16);
}

// XOR-swizzled byte offset into s_im: [row][wo][16 bf16] = 32 B per (row,wo).
// XOR byte bits [6:4] with wo bits [4:2] -> spreads stride-128B accesses.
__device__ __forceinline__ int im_off(int row, int wo, int half) {
    return (((row * 128 + wo) * 32) + half * 16) ^ (((wo >> 2) & 7) << 4);
}

// ---------------- one-time prep: weight transpose->bf16 + softplus ---------
__global__ void prep_kernel(const float* __restrict__ w_mu,
                            const float* __restrict__ w_sigma,
                            unsigned short* __restrict__ w_bf,
                            float* __restrict__ sp_out) {
    const int tid = threadIdx.x;       // 256
    const int n = tid >> 2;            // 64 rows, 4 threads each
    const int kbase = (tid & 3) * 26;  // 4*26 = 104
#pragma unroll
    for (int kk = 0; kk < 26; ++kk) {
        const int k = kbase + kk;
        float v = 0.f;
        if (k < 80) {
            const int r = k >> 4, t = k & 15;
            if (t < 15) v = w_mu[(r * 15 + t) * KN + n];
        }
        w_bf[n * KP + k] = f2bf(v);
    }
    if (tid < KN) sp_out[tid] = log1pf(expf(w_sigma[tid]));
}

// ---------------- KL scalar kernel (one wave) ----------------
__global__ void kl_kernel(const float* __restrict__ w_mu,
                          const float* __restrict__ w_sigma,
                          float* __restrict__ out_kl) {
    int kn = threadIdx.x;  // 64 threads
    float s = 0.f;
#pragma unroll
    for (int i = 0; i < 75; ++i) {
        float m = w_mu[i * KN + kn];
        s = fmaf(m, m, s);
    }
    float lv = w_sigma[kn];
    float sp = log1pf(expf(lv));
    float val = 1.0f + lv - sp - s * (1.0f / 75.0f);
#pragma unroll
    for (int off = 32; off > 0; off >>= 1) val += __shfl_down(val, off);
    if (kn == 0) {
        float kl = -(val / 64.0f);
        if (isnan(kl) || isinf(kl)) kl = 1e-5f;
        out_kl[0] = kl;
    }
}

// im2col fill: wave-uniform alignment class. OFF = (3*wo) mod 4, constexpr.
// Loads 4 (OFF<2) or 5 (OFF>=2) aligned float4; t=15 slot written 0.
// All loads proven in-bounds for wo<124; wo>=124 entries written as zeros.
template <int OFF>
__device__ __forceinline__ void im_fill(const float* __restrict__ mu_in,
                                        unsigned short* s_im, int b, int ho0,
                                        int lane, int wo) {
#pragma unroll
    for (int j = 0; j < 4; ++j) {
        const int row = ((lane >> 5) << 2) + j;  // 0..7
        uint4* dst0 =
            reinterpret_cast<uint4*>((char*)s_im + im_off(row, wo, 0));
        uint4* dst1 =
            reinterpret_cast<uint4*>((char*)s_im + im_off(row, wo, 1));
        if (wo >= 124) {
            *dst0 = make_uint4(0u, 0u, 0u, 0u);
            *dst1 = make_uint4(0u, 0u, 0u, 0u);
            continue;
        }
        const float* p =
            mu_in + ((size_t)(b * 128 + ho0 + row) * 384 + wo * 3 - OFF);
        float w[20];
        float4 f;
        f = reinterpret_cast<const float4*>(p)[0];
        w[0] = f.x; w[1] = f.y; w[2] = f.z; w[3] = f.w;
        f = reinterpret_cast<const float4*>(p)[1];
        w[4] = f.x; w[5] = f.y; w[6] = f.z; w[7] = f.w;
        f = reinterpret_cast<const float4*>(p)[2];
        w[8] = f.x; w[9] = f.y; w[10] = f.z; w[11] = f.w;
        f = reinterpret_cast<const float4*>(p)[3];
        w[12] = f.x; w[13] = f.y; w[14] = f.z; w[15] = f.w;
        if (OFF >= 2) {
            f = reinterpret_cast<const float4*>(p)[4];
            w[16] = f.x; w[17] = f.y; w[18] = f.z; w[19] = f.w;
        } else {
            w[16] = 0.f; w[17] = 0.f; w[18] = 0.f; w[19] = 0.f;
        }
        unsigned u0 = pack2(w[OFF + 0], w[OFF + 1]);
        unsigned u1 = pack2(w[OFF + 2], w[OFF + 3]);
        unsigned u2 = pack2(w[OFF + 4], w[OFF + 5]);
        unsigned u3 = pack2(w[OFF + 6], w[OFF + 7]);
        unsigned u4 = pack2(w[OFF + 8], w[OFF + 9]);
        unsigned u5 = pack2(w[OFF + 10], w[OFF + 11]);
        unsigned u6 = pack2(w[OFF + 12], w[OFF + 13]);
        unsigned u7 = pack2(w[OFF + 14], 0.0f);  // t=15: weight is zero
        *dst0 = make_uint4(u0, u1, u2, u3);
        *dst1 = make_uint4(u4, u5, u6, u7);
    }
}

// ---------------- main conv + Sigma kernel ----------------
// One block per (b, ho-group of 4). 256 threads = 4 waves.
// GEMM per ho: A = weights (M=64 kn), B = sliding-window im2col (N=128 wo),
// K=96. s_im[8][128][16] shared across the 4 ho's (ho uses rows hl..hl+4).
__global__ __launch_bounds__(256, 4) void conv_kernel(
    const float* __restrict__ mu_in,
    const unsigned short* __restrict__ w_bf,
    const float* __restrict__ sp_in,
    float* __restrict__ mu_out,
    float* __restrict__ sig_out) {

    __shared__ __align__(16) unsigned short s_im[8 * 128 * 16];  // 32 KB
    __shared__ __align__(16) float s_cs[8 * 128];                // 4 KB
    __shared__ float s_ssn[4 * 128];                             // 2 KB
    __shared__ float s_sp[KN];

    const int bid = blockIdx.x;
    const int b = bid / NG;
    const int ho0 = (bid % NG) * 4;
    const int tid = threadIdx.x;
    const int lane = tid & 63;
    const int wid = tid >> 6;
    const int llo = lane & 15;
    const int lhi = lane >> 4;

    // A fragments (weights) straight from L2-hot global -> regs (48 VGPR)
    bfrag8 afr[4][3];
#pragma unroll
    for (int mt = 0; mt < 4; ++mt)
#pragma unroll
        for (int ks = 0; ks < 3; ++ks)
            afr[mt][ks] = *reinterpret_cast<const bfrag8*>(
                &w_bf[(mt * 16 + llo) * KP + ks * 32 + lhi * 8]);
    if (tid < KN) s_sp[tid] = sp_in[tid];

    // ---- phase 1: per-(row, col) channel sum-of-squares (f32 exact) ----
    {
        const int r = tid >> 5;          // 0..7
        const int c4 = (tid & 31) << 2;  // 0..124
        const float* p = mu_in + ((size_t)(b * 128 + ho0 + r) * 384 + c4 * 3);
        float4 f0 = reinterpret_cast<const float4*>(p)[0];
        float4 f1 = reinterpret_cast<const float4*>(p)[1];
        float4 f2 = reinterpret_cast<const float4*>(p)[2];
        float4 cs;
        cs.x = f0.x * f0.x + f0.y * f0.y + f0.z * f0.z;
        cs.y = f0.w * f0.w + f1.x * f1.x + f1.y * f1.y;
        cs.z = f1.z * f1.z + f1.w * f1.w + f2.x * f2.x;
        cs.w = f2.y * f2.y + f2.z * f2.z + f2.w * f2.w;
        *reinterpret_cast<float4*>(&s_cs[r * 128 + c4]) = cs;
    }

    // ---- phase 2: im2col (each wave owns one wo mod-4 class) ----
    {
        const int wo = wid + ((lane & 31) << 2);
        switch (wid) {  // OFF = (3*class) mod 4
            case 0: im_fill<0>(mu_in, s_im, b, ho0, lane, wo); break;
            case 1: im_fill<3>(mu_in, s_im, b, ho0, lane, wo); break;
            case 2: im_fill<2>(mu_in, s_im, b, ho0, lane, wo); break;
            default: im_fill<1>(mu_in, s_im, b, ho0, lane, wo); break;
        }
    }
    __syncthreads();

    // ---- ssn[hl][wo] = (sum 5x5 window of cs) / 75 ----
    for (int i = tid; i < 512; i += 256) {
        const int hl = i >> 7, wo = i & 127;
        float v = 0.f;
        if (wo < HO) {
            float s = 0.f;
#pragma unroll
            for (int r = 0; r < 5; ++r)
#pragma unroll
                for (int d = 0; d < 5; ++d) s += s_cs[(hl + r) * 128 + wo + d];
            v = s * (1.0f / 75.0f);
        }
        s_ssn[hl * 128 + wo] = v;
    }
    __syncthreads();

    // ---- MFMA + store, 4 ho's back-to-back (stores spread over lifetime) --
    ffrag4 acc[2][4];
#pragma unroll
    for (int hl = 0; hl < 4; ++hl) {
#pragma unroll
        for (int nt = 0; nt < 2; ++nt)
#pragma unroll
            for (int mt = 0; mt < 4; ++mt)
                acc[nt][mt] = (ffrag4){0.f, 0.f, 0.f, 0.f};

#pragma unroll
        for (int nt = 0; nt < 2; ++nt) {
            const int wo = (wid * 2 + nt) * 16 + llo;
#pragma unroll
            for (int ks = 0; ks < 3; ++ks) {
                const int k0 = ks * 32 + lhi * 8;
                const int r = k0 >> 4;  // 0..5 (5 => k>=80: zero operand)
                bfrag8 bfr = (bfrag8){0, 0, 0, 0, 0, 0, 0, 0};
                if (r < 5) {
                    bfr = *reinterpret_cast<const bfrag8*>(
                        (char*)s_im + im_off(hl + r, wo, (k0 & 15) >> 3));
                }
#pragma unroll
                for (int mt = 0; mt < 4; ++mt)
                    acc[nt][mt] = __builtin_amdgcn_mfma_f32_16x16x32_bf16(
                        afr[mt][ks], bfr, acc[nt][mt], 0, 0, 0);
            }
        }

        const size_t orow = (size_t)(b * HO + ho0 + hl) * (size_t)(HO * KN);
#pragma unroll
        for (int nt = 0; nt < 2; ++nt) {
            const int wo = (wid * 2 + nt) * 16 + llo;
            if (wo < HO) {
                const float ssn = s_ssn[hl * 128 + wo];
                const size_t obase = orow + (size_t)wo * KN;
#pragma unroll
                for (int mt = 0; mt < 4; ++mt) {
                    const int knb = mt * 16 + lhi * 4;
                    const float4 sp4 =
                        *reinterpret_cast<const float4*>(&s_sp[knb]);
                    *reinterpret_cast<float4*>(&mu_out[obase + knb]) =
                        make_float4(acc[nt][mt][0], acc[nt][mt][1],
                                    acc[nt][mt][2], acc[nt][mt][3]);
                    *reinterpret_cast<float4*>(&sig_out[obase + knb]) =
                        make_float4(sp4.x * ssn, sp4.y * ssn, sp4.z * ssn,
                                    sp4.w * ssn);
                }
            }
        }
    }
}

extern "C" void kernel_launch(void* const* d_in, const int* in_sizes, int n_in,
                              void* d_out, int out_size, void* d_ws,
                              size_t ws_size, hipStream_t stream) {
    const float* mu_in = (const float*)d_in[0];
    const float* w_mu = (const float*)d_in[1];
    const float* w_sigma = (const float*)d_in[2];
    float* out = (float*)d_out;

    float* mu_out = out;             // N floats
    float* sig_out = out + NOUT;     // N floats
    float* kl_out = out + 2 * NOUT;  // 1 float

    unsigned short* w_bf = (unsigned short*)d_ws;        // 13312 B
    float* sp_ws = (float*)((char*)d_ws + KN * KP * 2);  // 256 B

    prep_kernel<<<1, 256, 0, stream>>>(w_mu, w_sigma, w_bf, sp_ws);
    conv_kernel<<<128 * NG, 256, 0, stream>>>(mu_in, w_bf, sp_ws, mu_out,
                                              sig_out);
    kl_kernel<<<1, 64, 0, stream>>>(w_mu, w_sigma, kl_out);
}